// Round 16
// baseline (277.647 us; speedup 1.0000x reference)
//
#include <hip/hip_runtime.h>

#define NROWS 65536   // B*T
#define DIM   256
#define VCB   2048

typedef _Float16 f16;
typedef _Float16 f16x8 __attribute__((ext_vector_type(8)));
typedef float    f32x4 __attribute__((ext_vector_type(4)));

// ---------------- ws layout (bytes) ----------------
// [0,        262144)  idx        int[NROWS]
// [262144,   270336)  hist       uint[VCB]
// [270336,   272384)  loss_part  double[256]
// [272384,   280576)  enorm      float[VCB]
// [524288,  1572864)  e_hi       f16[VCB*DIM]
// [1572864, 2621440)  e_lo       f16[VCB*DIM]

__device__ __forceinline__ void async16(void* lds, const void* g) {
  __builtin_amdgcn_global_load_lds(
      (const __attribute__((address_space(1))) void*)g,
      (__attribute__((address_space(3))) void*)lds, 16, 0, 0);
}

// fp32 -> (f16 hi, f16 lo) split — codebook only
__global__ __launch_bounds__(256) void convert_kernel(
    const float4* __restrict__ src, short4* __restrict__ dhi,
    short4* __restrict__ dlo, int n4) {
  int stride = gridDim.x * 256;
  for (int i = blockIdx.x * 256 + threadIdx.x; i < n4; i += stride) {
    float4 v = src[i];
    union { f16 h[4]; short4 s; } H, L;
    H.h[0] = (f16)v.x; H.h[1] = (f16)v.y; H.h[2] = (f16)v.z; H.h[3] = (f16)v.w;
    L.h[0] = (f16)(v.x - (float)H.h[0]);
    L.h[1] = (f16)(v.y - (float)H.h[1]);
    L.h[2] = (f16)(v.z - (float)H.h[2]);
    L.h[3] = (f16)(v.w - (float)H.h[3]);
    dhi[i] = H.s; dlo[i] = L.s;
  }
}

// zero hist + loss partials, compute ||e_j||^2 (one wave per codebook row), fp32
__global__ __launch_bounds__(256) void prep_kernel(
    const float* __restrict__ e, float* __restrict__ enorm,
    unsigned int* __restrict__ hist, double* __restrict__ loss_part) {
  int tid = threadIdx.x;
  int gt = blockIdx.x * 256 + tid;
  if (gt < VCB) hist[gt] = 0u;
  if (gt < 256) loss_part[gt] = 0.0;
  int wid  = gt >> 6;
  int lane = tid & 63;
  if (wid < VCB) {
    const float4* row = (const float4*)(e + (size_t)wid * DIM);
    float4 v = row[lane];
    float s = v.x*v.x + v.y*v.y + v.z*v.z + v.w*v.w;
    #pragma unroll
    for (int off = 32; off; off >>= 1) s += __shfl_xor(s, off);
    if (lane == 0) enorm[wid] = s;
  }
}

// Fused split-f16 MFMA distance GEMM + row argmin — WAVE-AUTONOMOUS.
// Block = 4 waves / 256 threads, A-tile = 64 rows x 256 k (hi+lo, 64 KB LDS,
// written once by the fused z-convert prologue, then read-only). Each wave
// owns 512 cols (8 chunks of 64) and stages its B tiles into WAVE-PRIVATE
// LDS double-buffers -> the main loop has NO barriers; per-wave counted
// vmcnt(8) is the only synchronization. Loss via minv (r15 trick).
__global__ __launch_bounds__(256) void argmin_kernel(
    const float* __restrict__ z,
    const f16* __restrict__ eh, const f16* __restrict__ el,
    const float* __restrict__ enorm,
    int* __restrict__ idx_out, unsigned int* __restrict__ hist,
    double* __restrict__ loss_part) {
  // A: per kt tile 8 KB = hi [0,4096)B + lo [4096,8192)B, [64 rows][32 f16]
  __shared__ f16 ldsA[8][4096];        // 64 KB, resident
  // B: [wave][buf]: hi [0,2048) f16 + lo [2048,4096) f16  ([64 cols][32 k])
  __shared__ f16 ldsB[4][2][4096];     // 64 KB

  const int tid  = threadIdx.x;
  const int wid  = tid >> 6;        // 0..3 (wave)
  const int lane = tid & 63;
  const int lrow = lane & 15;       // frag row/col index
  const int lq   = lane >> 4;       // k-chunk 0..3
  const int rbase = blockIdx.x * 64;

  // ---- prologue: reg-stage z fp32 -> hi/lo split -> swizzled ds_write ----
  {
    const int row = tid >> 2;       // 0..63
    const int q   = tid & 3;        // 64-col span
    const float* zrow = z + (size_t)(rbase + row) * DIM + q * 64;
    const int sw = (row >> 1) & 3;
    float zs = 0.f;
    #pragma unroll
    for (int f = 0; f < 16; ++f) {
      float4 v = *(const float4*)(zrow + f * 4);
      int col4   = q * 64 + f * 4;
      int kt     = col4 >> 5;
      int ko     = col4 & 31;
      int chunk  = ko >> 3;
      int within = (ko & 7) * 2;
      int addr = kt * 8192 + row * 64 + ((chunk ^ sw) << 4) + within;
      union { f16 h[4]; short4 s4; } H, L;
      H.h[0] = (f16)v.x; H.h[1] = (f16)v.y; H.h[2] = (f16)v.z; H.h[3] = (f16)v.w;
      L.h[0] = (f16)(v.x - (float)H.h[0]);
      L.h[1] = (f16)(v.y - (float)H.h[1]);
      L.h[2] = (f16)(v.z - (float)H.h[2]);
      L.h[3] = (f16)(v.w - (float)H.h[3]);
      *(short4*)((char*)ldsA + addr)        = H.s4;
      *(short4*)((char*)ldsA + addr + 4096) = L.s4;
      zs += v.x*v.x + v.y*v.y + v.z*v.z + v.w*v.w;
    }
    #pragma unroll
    for (int off = 32; off; off >>= 1) zs += __shfl_xor(zs, off);
    if (lane == 0) atomicAdd(&loss_part[blockIdx.x & 255], (double)zs);
  }
  __syncthreads();   // A resident (all waves read all rows)

  // wave-private B staging: 8 global_load_lds per step (4 hi + 4 lo)
  auto stageB = [&](int b, int cc, int kt) {
    f16* base = &ldsB[wid][b][0];
    const int vcol = wid * 512 + cc * 64;
    #pragma unroll
    for (int i = 0; i < 4; ++i) {
      int col = i * 16 + (lane >> 2);
      int swc = (col >> 1) & 3;
      size_t goff = (size_t)(vcol + col) * DIM + (kt << 5) + (((lane & 3) ^ swc) << 3);
      async16(base +        i * 512 + lane * 8, eh + goff);
      async16(base + 2048 + i * 512 + lane * 8, el + goff);
    }
  };

  float minv[4][4];
  int   mini[4][4];
  #pragma unroll
  for (int m = 0; m < 4; ++m)
    #pragma unroll
    for (int r = 0; r < 4; ++r) { minv[m][r] = 3.4e38f; mini[m][r] = 0; }

  const int cchunk = lq ^ ((lrow >> 1) & 3);

  int mybuf = 0;
  stageB(0, 0, 0);

  for (int cc = 0; cc < 8; ++cc) {
    f32x4 acc[4][4];
    #pragma unroll
    for (int m = 0; m < 4; ++m)
      #pragma unroll
      for (int n = 0; n < 4; ++n) {
        f32x4 zz = {0.f, 0.f, 0.f, 0.f};
        acc[m][n] = zz;
      }

    for (int kt = 0; kt < 8; ++kt) {
      // prefetch next step into the other private buffer (wrap -> dummy)
      {
        int nkt = kt + 1, ncc = cc;
        if (nkt == 8) { nkt = 0; ++ncc; if (ncc == 8) ncc = 0; }
        stageB(mybuf ^ 1, ncc, nkt);
      }
      // per-wave counted wait: previous step's 8 loads have landed
      asm volatile("s_waitcnt vmcnt(8)" ::: "memory");
      __builtin_amdgcn_sched_barrier(0);

      const char* abase = (const char*)ldsA + kt * 8192;
      f16x8 ah[4], al[4];
      #pragma unroll
      for (int m = 0; m < 4; ++m) {
        int row = m * 16 + lrow;
        int off = row * 64 + cchunk * 16;
        ah[m] = *(const f16x8*)(abase + off);
        al[m] = *(const f16x8*)(abase + 4096 + off);
      }
      const char* bbase = (const char*)&ldsB[wid][mybuf][0];
      __builtin_amdgcn_s_setprio(1);
      #pragma unroll
      for (int n = 0; n < 4; ++n) {
        int col = n * 16 + lrow;
        int off = col * 64 + cchunk * 16;
        f16x8 bh = *(const f16x8*)(bbase + off);
        f16x8 bl = *(const f16x8*)(bbase + 4096 + off);
        #pragma unroll
        for (int m = 0; m < 4; ++m) {
          acc[m][n] = __builtin_amdgcn_mfma_f32_16x16x32_f16(ah[m], bh, acc[m][n], 0, 0, 0);
          acc[m][n] = __builtin_amdgcn_mfma_f32_16x16x32_f16(ah[m], bl, acc[m][n], 0, 0, 0);
          acc[m][n] = __builtin_amdgcn_mfma_f32_16x16x32_f16(al[m], bh, acc[m][n], 0, 0, 0);
        }
      }
      __builtin_amdgcn_s_setprio(0);
      mybuf ^= 1;
    }

    // chunk epilogue: C/D layout col=lane&15, row=(lane>>4)*4+reg (m89/m91)
    const int cbase = wid * 512 + cc * 64;
    #pragma unroll
    for (int n = 0; n < 4; ++n) {
      int j = cbase + n * 16 + lrow;
      float en = enorm[j];
      #pragma unroll
      for (int m = 0; m < 4; ++m)
        #pragma unroll
        for (int r = 0; r < 4; ++r) {
          float s = fmaf(-2.f, acc[m][n][r], en);
          if (s < minv[m][r]) { minv[m][r] = s; mini[m][r] = j; }
        }
    }
  }

  // drain the trailing dummy stage before aliasing ldsB as merge scratch
  asm volatile("s_waitcnt vmcnt(0)" ::: "memory");

  // reduce across the 16 lanes (lane bits 0..3) sharing each row; first-idx tie-break
  #pragma unroll
  for (int off = 1; off < 16; off <<= 1) {
    #pragma unroll
    for (int m = 0; m < 4; ++m)
      #pragma unroll
      for (int r = 0; r < 4; ++r) {
        float ov = __shfl_xor(minv[m][r], off);
        int   oi = __shfl_xor(mini[m][r], off);
        if (ov < minv[m][r] || (ov == minv[m][r] && oi < mini[m][r])) {
          minv[m][r] = ov; mini[m][r] = oi;
        }
      }
  }

  // cross-wave merge over the 4 waves; scratch aliases ldsB
  __syncthreads();
  float* sxv = (float*)&ldsB[0][0][0];    // [3][64]
  int*   sxi = (int*)(sxv + 3 * 64);
  if (wid != 0 && lrow == 0) {
    #pragma unroll
    for (int m = 0; m < 4; ++m)
      #pragma unroll
      for (int r = 0; r < 4; ++r) {
        int li = m * 16 + lq * 4 + r;
        sxv[(wid - 1) * 64 + li] = minv[m][r];
        sxi[(wid - 1) * 64 + li] = mini[m][r];
      }
  }
  __syncthreads();
  if (wid == 0 && lrow == 0) {
    float lsum = 0.f;
    #pragma unroll
    for (int m = 0; m < 4; ++m)
      #pragma unroll
      for (int r = 0; r < 4; ++r) {
        int li = m * 16 + lq * 4 + r;
        float v  = minv[m][r];
        int   bi = mini[m][r];
        #pragma unroll
        for (int g = 0; g < 3; ++g) {
          float ov = sxv[g * 64 + li];
          int   oi = sxi[g * 64 + li];
          if (ov < v || (ov == v && oi < bi)) { v = ov; bi = oi; }
        }
        idx_out[rbase + li] = bi;
        atomicAdd(&hist[bi], 1u);
        lsum += v;                        // v = d_min - ||z_row||^2
      }
    lsum += __shfl_xor(lsum, 16);
    lsum += __shfl_xor(lsum, 32);
    if (lane == 0) atomicAdd(&loss_part[blockIdx.x & 255], (double)lsum);
  }
}

// gather z_q = e[idx] (exact fp32), write z_q_st + float indices
__global__ __launch_bounds__(256) void gather_kernel(
    const float* __restrict__ e, const int* __restrict__ idx,
    float* __restrict__ zq_out, float* __restrict__ idxf_out) {
  int tid  = threadIdx.x;
  int w    = tid >> 6;
  int lane = tid & 63;
  int n    = blockIdx.x * 4 + w;

  int ci = idx[n];
  const float4* er = (const float4*)(e + (size_t)ci * DIM);
  ((float4*)(zq_out + (size_t)n * DIM))[lane] = er[lane];
  if (lane == 0) idxf_out[n] = (float)ci;
}

__global__ __launch_bounds__(256) void finalize_kernel(
    const unsigned int* __restrict__ hist, const double* __restrict__ loss_part,
    float* __restrict__ out) {
  __shared__ double lsh[4];
  __shared__ float  hsh[4];
  __shared__ float  denom_sh;
  int tid = threadIdx.x, lane = tid & 63, w = tid >> 6;

  float hs = 0.f;
  for (int j = tid; j < VCB; j += 256) hs += (float)hist[j];
  double ls = loss_part[tid];
  #pragma unroll
  for (int off = 32; off; off >>= 1) {
    hs += __shfl_xor(hs, off);
    ls += __shfl_xor(ls, off);
  }
  if (lane == 0) { lsh[w] = ls; hsh[w] = hs; }
  __syncthreads();
  if (tid == 0) {
    double lt = lsh[0] + lsh[1] + lsh[2] + lsh[3];
    float  ht = hsh[0] + hsh[1] + hsh[2] + hsh[3];
    out[0] = (float)(lt / (double)((size_t)NROWS * DIM));
    denom_sh = ht + 1e-8f;
  }
  __syncthreads();
  float denom = denom_sh;
  float* prob = out + 1 + (size_t)NROWS * DIM + NROWS;
  for (int j = tid; j < VCB; j += 256) prob[j] = (float)hist[j] / denom;
}

extern "C" void kernel_launch(void* const* d_in, const int* in_sizes, int n_in,
                              void* d_out, int out_size, void* d_ws, size_t ws_size,
                              hipStream_t stream) {
  (void)in_sizes; (void)n_in; (void)out_size; (void)ws_size;
  const float* z = (const float*)d_in[0];
  const float* e = (const float*)d_in[1];
  float* out = (float*)d_out;
  char*  ws  = (char*)d_ws;

  int*          idx       = (int*)ws;
  unsigned int* hist      = (unsigned int*)(ws + 262144);
  double*       loss_part = (double*)(ws + 270336);
  float*        enorm     = (float*)(ws + 272384);
  f16*          e_hi      = (f16*)(ws + 524288);
  f16*          e_lo      = (f16*)(ws + 1572864);

  float* out_zq  = out + 1;
  float* out_idx = out + 1 + (size_t)NROWS * DIM;

  convert_kernel<<<128, 256, 0, stream>>>(
      (const float4*)e, (short4*)e_hi, (short4*)e_lo, VCB * DIM / 4);
  prep_kernel<<<512, 256, 0, stream>>>(e, enorm, hist, loss_part);
  argmin_kernel<<<NROWS / 64, 256, 0, stream>>>(
      z, e_hi, e_lo, enorm, idx, hist, loss_part);
  gather_kernel<<<NROWS / 4, 256, 0, stream>>>(e, idx, out_zq, out_idx);
  finalize_kernel<<<1, 256, 0, stream>>>(hist, loss_part, out);
}